// Round 2
// baseline (672.630 us; speedup 1.0000x reference)
//
#include <hip/hip_runtime.h>
#include <stdint.h>

#define L2E 1.44269504088896f

static __device__ __forceinline__ float wsum(float v) {
    #pragma unroll
    for (int m = 1; m < 64; m <<= 1) v += __shfl_xor(v, m, 64);
    return v;
}
static __device__ __forceinline__ float sigm(float x) {
    return 1.0f / (1.0f + __builtin_amdgcn_exp2f(-x * L2E));
}
static __device__ __forceinline__ float tanh_(float x) {
    const float ax = fabsf(x);
    const float t = __builtin_amdgcn_exp2f(-2.0f * ax * L2E);
    const float r = (1.0f - t) / (1.0f + t);
    return (x < 0.f) ? -r : r;
}

// DPP helper: returns neighbor's value per compile-time ctrl (VALU-rate).
template <int CTRL>
static __device__ __forceinline__ float dppterm(float v) {
    return __int_as_float(__builtin_amdgcn_update_dpp(
        0, __float_as_int(v), CTRL, 0xF, 0xF, true));
}
// Butterfly sum over 8 contiguous lanes (chunk = lane&7). All adds
// commutative -> bitwise-identical result in all 8 lanes.
static __device__ __forceinline__ float red8(float v) {
    v += dppterm<0xB1>(v);    // quad_perm(1,0,3,2)  = xor1
    v += dppterm<0x4E>(v);    // quad_perm(2,3,0,1)  = xor2
    v += dppterm<0x141>(v);   // row_half_mirror     = xor7 (quads merged)
    return v;
}

// ---------------------------------------------------------------------------
// init: fused weight transpose (wihT/whhT/WkT) + slot broadcast + iter-0
// gkq/aux + per-iteration tail counters. grid 112 x 256.
// ---------------------------------------------------------------------------
__global__ __launch_bounds__(256) void init_kernel(
    const float* __restrict__ s0,
    const float* __restrict__ lsg, const float* __restrict__ lsb,
    const float* __restrict__ Wq,  const float* __restrict__ Wk,
    const float* __restrict__ lig, const float* __restrict__ lib,
    const float* __restrict__ wih, const float* __restrict__ whh,
    float* __restrict__ slots, float* __restrict__ gkq, float* __restrict__ aux,
    float* __restrict__ wihT, float* __restrict__ whhT, float* __restrict__ WkT,
    int* __restrict__ cnt)
{
    __shared__ float wkT[4096];
    __shared__ float scr[4][64];
    const int tid = threadIdx.x, lane = tid & 63, wv = tid >> 6;
    const int idx = blockIdx.x * 256 + tid;

    if (idx < 192) cnt[idx] = 0;                // 3 iters x 64 batches

    if (idx < 12288) {
        const int i = idx / 192, j = idx - i * 192;
        wihT[idx] = wih[j * 64 + i];
    } else if (idx < 24576) {
        const int o = idx - 12288;
        const int i = o / 192, j = o - i * 192;
        whhT[o] = whh[j * 64 + i];
    } else {
        const int o = idx - 24576;
        const int p = o >> 6, d = o & 63;
        WkT[o] = Wk[d * 64 + p];
    }

    const int r = blockIdx.x * 4 + wv;          // 0..447
    const int s = r % 7;
    #pragma unroll
    for (int i = tid; i < 4096; i += 256) {
        const int d = i >> 6, p = i & 63;
        wkT[p * 64 + d] = Wk[i];
    }
    const float h = s0[s * 64 + lane];
    slots[r * 64 + lane] = h;
    __syncthreads();

    const float mean = wsum(h) * (1.0f / 64.0f);
    const float d = h - mean;
    const float var = wsum(d * d) * (1.0f / 64.0f);
    const float rs = rsqrtf(var + 1e-5f);
    const float sn = d * rs * lsg[lane] + lsb[lane];
    scr[wv][lane] = sn;
    __syncthreads();
    float q = 0.f;
    #pragma unroll 8
    for (int i = 0; i < 64; ++i) q = fmaf(scr[wv][i], Wq[i * 64 + lane], q);
    q *= 0.125f;
    __syncthreads();
    scr[wv][lane] = q;
    __syncthreads();
    float kq = 0.f;
    #pragma unroll 8
    for (int p = 0; p < 64; ++p) kq = fmaf(wkT[p * 64 + lane], scr[wv][p], kq);
    const float bk = wsum(lib[lane] * kq);
    const float gk = lig[lane] * kq;
    const float g1 = wsum(gk);
    gkq[r * 64 + lane] = gk;
    if (lane == 0) { aux[r * 2] = g1; aux[r * 2 + 1] = bk; }
}

// ---------------------------------------------------------------------------
// iter v4: attn (v3 register/DPP flow, depth-2 prefetch) + fused per-batch
// update via last-block atomic gate. grid B*16 = 1024 x 256.
//
// attn: lane = rowslot(3b)*8 + chunk(3b); gk[7][8] in VGPRs; x direct
// global->reg with 2-group-deep software pipeline; DPP xor1/2/7 row
// reduction; Yacc[7][8] in regs; epilogue DPP xor8 -> ybuf -> Ypart
// ([b][16][456] = 448 Y + 7 colsums + pad).
//
// update (tail block per batch, after cnt[b] hits 16): Y/C global reduce ->
// per-wave per-slot chain (aoc -> u=aoc@Wv -> GRU -> MLP -> slots, + next-
// iter LN/q/kq or final out). Release/acquire via __threadfence around the
// atomic (device-scope), standard split-K last-block pattern.
// ---------------------------------------------------------------------------
__global__ __launch_bounds__(256, 2) void iter_kernel(
    const float* __restrict__ x,
    float* __restrict__ gkq, float* __restrict__ aux,
    float* __restrict__ Ypart, float* __restrict__ slots,
    const float* __restrict__ Wv,
    const float* __restrict__ wihT, const float* __restrict__ whhT,
    const float* __restrict__ bih,  const float* __restrict__ bhh,
    const float* __restrict__ w1,   const float* __restrict__ b1,
    const float* __restrict__ w2,   const float* __restrict__ b2,
    const float* __restrict__ lsg,  const float* __restrict__ lsb,
    const float* __restrict__ Wq,   const float* __restrict__ WkT,
    const float* __restrict__ lig,  const float* __restrict__ lib,
    int* __restrict__ cnt, float* __restrict__ out, int last)
{
    __shared__ float ybuf[16][460];             // 29.4 KB
    __shared__ float wsYd[7][64];
    __shared__ float wsC[8];
    __shared__ float wss[4][4][64];             // per-wave update scratch
    __shared__ int lflag;
    const int tid = threadIdx.x, lane = tid & 63, wv = tid >> 6;
    const int b = blockIdx.x >> 4, chunk16 = blockIdx.x & 15;
    const int ck  = lane & 7;                   // dim-chunk 0..7
    const int rsl = lane >> 3;                  // row-slot 0..7

    // gk fragments -> registers (once)
    float gk[7][8];
    {
        const float4* gp = (const float4*)(gkq + b * 448 + ck * 8);
        #pragma unroll
        for (int s = 0; s < 7; ++s) {
            const float4 u0 = gp[s * 16], u1 = gp[s * 16 + 1];
            gk[s][0] = u0.x; gk[s][1] = u0.y; gk[s][2] = u0.z; gk[s][3] = u0.w;
            gk[s][4] = u1.x; gk[s][5] = u1.y; gk[s][6] = u1.z; gk[s][7] = u1.w;
        }
    }
    const float* ab = aux + b * 14;
    float g1[7], bk[7];
    #pragma unroll
    for (int s = 0; s < 7; ++s) { g1[s] = ab[2 * s]; bk[s] = ab[2 * s + 1]; }

    float Yacc[7][8];
    #pragma unroll
    for (int s = 0; s < 7; ++s)
        #pragma unroll
        for (int j = 0; j < 8; ++j) Yacc[s][j] = 0.f;
    float cacc[7] = {0.f, 0.f, 0.f, 0.f, 0.f, 0.f, 0.f};

    const float* rb = x + (((long)b * 4096) + chunk16 * 256 + wv * 64 + rsl) * 64
                        + ck * 8;

    auto process = [&](const float4& u0, const float4& u1) {
        const float xv[8] = {u0.x, u0.y, u0.z, u0.w, u1.x, u1.y, u1.z, u1.w};
        float sum = 0.f, ss = 0.f;
        #pragma unroll
        for (int j = 0; j < 8; ++j) { sum += xv[j]; ss = fmaf(xv[j], xv[j], ss); }
        float acc[7];
        #pragma unroll
        for (int s = 0; s < 7; ++s) {
            float a = 0.f;
            #pragma unroll
            for (int j = 0; j < 8; ++j) a = fmaf(xv[j], gk[s][j], a);
            acc[s] = a;
        }
        sum = red8(sum);
        ss  = red8(ss);
        #pragma unroll
        for (int s = 0; s < 7; ++s) acc[s] = red8(acc[s]);

        const float m   = sum * (1.0f / 64.0f);
        const float var = ss * (1.0f / 64.0f) - m * m;
        const float rs  = rsqrtf(var + 1e-5f);
        const float rsm = rs * m;
        float t[7];
        #pragma unroll
        for (int s = 0; s < 7; ++s)
            t[s] = fmaf(rs, acc[s], fmaf(-rsm, g1[s], bk[s]));
        float mx = t[0];
        #pragma unroll
        for (int s = 1; s < 7; ++s) mx = fmaxf(mx, t[s]);
        float e[7], se = 0.f;
        #pragma unroll
        for (int s = 0; s < 7; ++s) {
            e[s] = __builtin_amdgcn_exp2f((t[s] - mx) * L2E);
            se += e[s];
        }
        const float inv = 1.0f / se;
        #pragma unroll
        for (int s = 0; s < 7; ++s) {
            const float w = fmaf(e[s], inv, 1e-8f);
            cacc[s] += w;
            const float wrs = w * rs;
            #pragma unroll
            for (int j = 0; j < 8; ++j)
                Yacc[s][j] = fmaf(wrs, xv[j], Yacc[s][j]);
        }
    };

    // depth-2 software pipeline, unrolled by 2 (static register names)
    float4 pa0 = *(const float4*)(rb);
    float4 pa1 = *(const float4*)(rb + 4);
    float4 pb0 = *(const float4*)(rb + 512);
    float4 pb1 = *(const float4*)(rb + 516);
    #pragma unroll 1
    for (int g = 0; g < 8; g += 2) {
        const int g2 = (g + 2 < 8) ? g + 2 : 6;     // clamp: dead reload
        const int g3 = (g + 3 < 8) ? g + 3 : 7;
        const float4 na0 = *(const float4*)(rb + g2 * 512);
        const float4 na1 = *(const float4*)(rb + g2 * 512 + 4);
        process(pa0, pa1);
        const float4 nb0 = *(const float4*)(rb + g3 * 512);
        const float4 nb1 = *(const float4*)(rb + g3 * 512 + 4);
        process(pb0, pb1);
        pa0 = na0; pa1 = na1; pb0 = nb0; pb1 = nb1;
    }

    // pair rowslots via DPP xor8; rowslots 0,2,4,6 hold 4 sub-partials
    #pragma unroll
    for (int s = 0; s < 7; ++s) {
        #pragma unroll
        for (int j = 0; j < 8; ++j)
            Yacc[s][j] += dppterm<0x128>(Yacc[s][j]);
        cacc[s] += dppterm<0x128>(cacc[s]);
    }
    if (((lane >> 3) & 1) == 0) {
        const int sub = lane >> 4;              // 0..3
        float* yb = &ybuf[wv * 4 + sub][ck * 8];
        #pragma unroll
        for (int s = 0; s < 7; ++s) {
            #pragma unroll
            for (int j = 0; j < 8; ++j) yb[s * 64 + j] = Yacc[s][j];
        }
        if (ck == 0) {
            #pragma unroll
            for (int s = 0; s < 7; ++s)
                ybuf[wv * 4 + sub][448 + s] = cacc[s];
        }
    }
    __syncthreads();
    for (int i = tid; i < 455; i += 256) {
        float v = 0.f;
        #pragma unroll
        for (int p = 0; p < 16; ++p) v += ybuf[p][i];
        Ypart[((long)b * 16 + chunk16) * 456 + i] = v;
    }

    // ---- last-block gate (release: all threads fence, then one atomic) ----
    __threadfence();
    __syncthreads();
    if (tid == 0) {
        const int old = atomicAdd(&cnt[b], 1);
        lflag = (old == 15) ? 1 : 0;
    }
    __syncthreads();
    if (!lflag) return;
    __threadfence();                            // acquire

    // ---- fused update for batch b (7 slots) ----
    const float* Yb = Ypart + (long)b * 16 * 456;
    for (int o = tid; o < 448; o += 256) {
        float v = 0.f;
        #pragma unroll
        for (int c = 0; c < 16; ++c) v += Yb[c * 456 + o];
        wsYd[o >> 6][o & 63] = v;
    }
    if (tid < 7) {
        float v = 0.f;
        #pragma unroll
        for (int c = 0; c < 16; ++c) v += Yb[c * 456 + 448 + tid];
        wsC[tid] = v;
    }
    __syncthreads();

    float (*scr)[64] = wss[wv];
    #pragma unroll 1
    for (int sp = 0; sp < 2; ++sp) {
        const int s = wv + sp * 4;              // wv0:{0,4} wv1:{1,5} wv2:{2,6} wv3:{3}
        if (s >= 7) break;
        const int r = b * 7 + s;

        const float Yd = wsYd[s][lane];
        const float C  = wsC[s];
        const float Z  = wsum(Yd) * (1.0f / 64.0f);
        const float a  = (lig[lane] * (Yd - Z) + lib[lane] * C) / C;
        scr[0][lane] = a;
        float u = 0.f;
        #pragma unroll 8
        for (int i = 0; i < 64; ++i) u = fmaf(scr[0][i], Wv[i * 64 + lane], u);
        const float h = slots[r * 64 + lane];
        scr[1][lane] = u;
        scr[2][lane] = h;

        float gi0 = bih[lane], gi1 = bih[64 + lane], gi2 = bih[128 + lane];
        float gh0 = bhh[lane], gh1 = bhh[64 + lane], gh2 = bhh[128 + lane];
        #pragma unroll 4
        for (int i = 0; i < 64; ++i) {
            const float ui = scr[1][i], hi = scr[2][i];
            const float* wi = &wihT[i * 192];
            const float* wh = &whhT[i * 192];
            gi0 = fmaf(ui, wi[lane], gi0);
            gi1 = fmaf(ui, wi[64 + lane], gi1);
            gi2 = fmaf(ui, wi[128 + lane], gi2);
            gh0 = fmaf(hi, wh[lane], gh0);
            gh1 = fmaf(hi, wh[64 + lane], gh1);
            gh2 = fmaf(hi, wh[128 + lane], gh2);
        }
        const float rr = sigm(gi0 + gh0);
        const float zz = sigm(gi1 + gh1);
        const float nn = tanh_(gi2 + rr * gh2);
        const float hn = (1.f - zz) * nn + zz * h;
        scr[0][lane] = hn;

        float m0 = b1[lane], m1 = b1[64 + lane];
        #pragma unroll 8
        for (int i = 0; i < 64; ++i) {
            const float hi = scr[0][i];
            m0 = fmaf(hi, w1[i * 128 + lane], m0);
            m1 = fmaf(hi, w1[i * 128 + 64 + lane], m1);
        }
        scr[1][lane] = fmaxf(m0, 0.f);
        scr[2][lane] = fmaxf(m1, 0.f);

        float o2 = b2[lane];
        #pragma unroll 8
        for (int t = 0; t < 64; ++t)
            o2 = fmaf(scr[1][t], w2[t * 64 + lane], o2);
        #pragma unroll 8
        for (int t = 0; t < 64; ++t)
            o2 = fmaf(scr[2][t], w2[(64 + t) * 64 + lane], o2);
        const float snv = hn + o2;
        slots[r * 64 + lane] = snv;
        if (last) {
            out[r * 64 + lane] = snv;
        } else {
            const float mean = wsum(snv) * (1.0f / 64.0f);
            const float d = snv - mean;
            const float var = wsum(d * d) * (1.0f / 64.0f);
            const float rs = rsqrtf(var + 1e-5f);
            const float sn = d * rs * lsg[lane] + lsb[lane];
            scr[3][lane] = sn;
            float q = 0.f;
            #pragma unroll 8
            for (int i = 0; i < 64; ++i) q = fmaf(scr[3][i], Wq[i * 64 + lane], q);
            q *= 0.125f;
            scr[0][lane] = q;
            float kq = 0.f;
            #pragma unroll 8
            for (int p = 0; p < 64; ++p) kq = fmaf(WkT[p * 64 + lane], scr[0][p], kq);
            const float bk2 = wsum(lib[lane] * kq);
            const float gkv = lig[lane] * kq;
            const float g1v = wsum(gkv);
            gkq[r * 64 + lane] = gkv;
            if (lane == 0) { aux[r * 2] = g1v; aux[r * 2 + 1] = bk2; }
        }
    }
}

// ---------------------------------------------------------------------------
extern "C" void kernel_launch(void* const* d_in, const int* in_sizes, int n_in,
                              void* d_out, int out_size, void* d_ws, size_t ws_size,
                              hipStream_t stream)
{
    const float* x   = (const float*)d_in[0];
    const float* lig = (const float*)d_in[1];
    const float* lib = (const float*)d_in[2];
    const float* lsg = (const float*)d_in[3];
    const float* lsb = (const float*)d_in[4];
    const float* s0  = (const float*)d_in[5];
    const float* Wk  = (const float*)d_in[6];
    const float* Wv  = (const float*)d_in[7];
    const float* Wq  = (const float*)d_in[8];
    const float* wih = (const float*)d_in[9];
    const float* whh = (const float*)d_in[10];
    const float* bih = (const float*)d_in[11];
    const float* bhh = (const float*)d_in[12];
    const float* w1  = (const float*)d_in[13];
    const float* b1  = (const float*)d_in[14];
    const float* w2  = (const float*)d_in[15];
    const float* b2  = (const float*)d_in[16];

    float* f = (float*)d_ws;
    float* gkq   = f; f += 448 * 64;
    float* aux   = f; f += 448 * 2;
    float* slots = f; f += 448 * 64;
    float* Ypart = f; f += (long)64 * 16 * 456;
    float* wihT  = f; f += 64 * 192;
    float* whhT  = f; f += 64 * 192;
    float* WkT   = f; f += 64 * 64;
    int*   cnt   = (int*)f;  f += 192;

    init_kernel<<<112, 256, 0, stream>>>(s0, lsg, lsb, Wq, Wk, lig, lib,
                                         wih, whh, slots, gkq, aux,
                                         wihT, whhT, WkT, cnt);
    for (int it = 0; it < 3; ++it) {
        iter_kernel<<<1024, 256, 0, stream>>>(
            x, gkq, aux, Ypart, slots, Wv, wihT, whhT, bih, bhh,
            w1, b1, w2, b2, lsg, lsb, Wq, WkT, lig, lib,
            cnt + it * 64, (float*)d_out, it == 2);
    }
}

// Round 3
// 245.334 us; speedup vs baseline: 2.7417x; 2.7417x over previous
//
#include <hip/hip_runtime.h>
#include <stdint.h>

#define L2E 1.44269504088896f

static __device__ __forceinline__ float wsum(float v) {
    #pragma unroll
    for (int m = 1; m < 64; m <<= 1) v += __shfl_xor(v, m, 64);
    return v;
}
static __device__ __forceinline__ float sigm(float x) {
    return 1.0f / (1.0f + __builtin_amdgcn_exp2f(-x * L2E));
}
static __device__ __forceinline__ float tanh_(float x) {
    const float ax = fabsf(x);
    const float t = __builtin_amdgcn_exp2f(-2.0f * ax * L2E);
    const float r = (1.0f - t) / (1.0f + t);
    return (x < 0.f) ? -r : r;
}

// DPP helper: returns neighbor's value per compile-time ctrl (VALU-rate).
template <int CTRL>
static __device__ __forceinline__ float dppterm(float v) {
    return __int_as_float(__builtin_amdgcn_update_dpp(
        0, __float_as_int(v), CTRL, 0xF, 0xF, true));
}
// Butterfly sum over 16 contiguous lanes (one DPP row). xor1+xor2 give
// quad sums; ror4+ror8 rotate quad sums so every lane accumulates all 4.
// All adds commutative -> identical result in all 16 lanes.
static __device__ __forceinline__ float red16(float v) {
    v += dppterm<0xB1>(v);    // quad_perm(1,0,3,2)  = xor1
    v += dppterm<0x4E>(v);    // quad_perm(2,3,0,1)  = xor2
    v += dppterm<0x124>(v);   // row_ror:4
    v += dppterm<0x128>(v);   // row_ror:8
    return v;
}

// ---------------------------------------------------------------------------
// init: fused weight transpose (wihT/whhT/WkT) + slot broadcast + iter-0
// gkq/aux. grid 112 x 256 (28672 thr = exact transpose element count).
// ---------------------------------------------------------------------------
__global__ __launch_bounds__(256) void init_kernel(
    const float* __restrict__ s0,
    const float* __restrict__ lsg, const float* __restrict__ lsb,
    const float* __restrict__ Wq,  const float* __restrict__ Wk,
    const float* __restrict__ lig, const float* __restrict__ lib,
    const float* __restrict__ wih, const float* __restrict__ whh,
    float* __restrict__ slots, float* __restrict__ gkq, float* __restrict__ aux,
    float* __restrict__ wihT, float* __restrict__ whhT, float* __restrict__ WkT)
{
    __shared__ float wkT[4096];
    __shared__ float scr[4][64];
    const int tid = threadIdx.x, lane = tid & 63, wv = tid >> 6;
    const int idx = blockIdx.x * 256 + tid;

    if (idx < 12288) {
        const int i = idx / 192, j = idx - i * 192;
        wihT[idx] = wih[j * 64 + i];
    } else if (idx < 24576) {
        const int o = idx - 12288;
        const int i = o / 192, j = o - i * 192;
        whhT[o] = whh[j * 64 + i];
    } else {
        const int o = idx - 24576;
        const int p = o >> 6, d = o & 63;
        WkT[o] = Wk[d * 64 + p];
    }

    const int r = blockIdx.x * 4 + wv;          // 0..447
    const int s = r % 7;
    #pragma unroll
    for (int i = tid; i < 4096; i += 256) {
        const int d = i >> 6, p = i & 63;
        wkT[p * 64 + d] = Wk[i];
    }
    const float h = s0[s * 64 + lane];
    slots[r * 64 + lane] = h;
    __syncthreads();

    const float mean = wsum(h) * (1.0f / 64.0f);
    const float d = h - mean;
    const float var = wsum(d * d) * (1.0f / 64.0f);
    const float rs = rsqrtf(var + 1e-5f);
    const float sn = d * rs * lsg[lane] + lsb[lane];
    scr[wv][lane] = sn;
    __syncthreads();
    float q = 0.f;
    #pragma unroll 8
    for (int i = 0; i < 64; ++i) q = fmaf(scr[wv][i], Wq[i * 64 + lane], q);
    q *= 0.125f;
    __syncthreads();
    scr[wv][lane] = q;
    __syncthreads();
    float kq = 0.f;
    #pragma unroll 8
    for (int p = 0; p < 64; ++p) kq = fmaf(wkT[p * 64 + lane], scr[wv][p], kq);
    const float bk = wsum(lib[lane] * kq);
    const float gk = lig[lane] * kq;
    const float g1 = wsum(gk);
    gkq[r * 64 + lane] = gk;
    if (lane == 0) { aux[r * 2] = g1; aux[r * 2 + 1] = bk; }
}

// ---------------------------------------------------------------------------
// attn v5 (occupancy-doubled): lane = rowslot(2b)*16 + chunk(4b). Each lane
// owns 4 dims (gk[7][4], Yacc[7][4] -> big arrays 56 VGPR, total ~110,
// forced <=128 via launch_bounds(256,4) -> 16 waves/CU, grid co-resident).
// Per group g (0..15): wave loads 4 full rows (1 KB dense, one float4/lane,
// depth-1 prefetch); 16-lane DPP butterfly (xor1/xor2/ror4/ror8) reduces
// {sum, ss, 7 dots}; redundant per-lane softmax; Y accumulated in regs.
// Epilogue: all 64 lanes write their (wv,rsl) partial -> ybuf[16][460]
// (16 partials, bank-clean), then the same 16-way reduce -> Ypart
// ([b][16][456] = 448 Y + 7 colsums + pad). grid B*16 = 1024 x 256.
// NO lambdas (R2 spill lesson: captured arrays must stay SROA-able).
// ---------------------------------------------------------------------------
__global__ __launch_bounds__(256, 4) void attn_kernel(
    const float* __restrict__ x,
    const float* __restrict__ gkq, const float* __restrict__ aux,
    float* __restrict__ Ypart)
{
    __shared__ float ybuf[16][460];             // 29.4 KB
    const int tid = threadIdx.x, lane = tid & 63, wv = tid >> 6;
    const int b = blockIdx.x >> 4, chunk16 = blockIdx.x & 15;
    const int ck  = lane & 15;                  // dim-chunk 0..15 (4 dims)
    const int rsl = lane >> 4;                  // row-slot 0..3

    // gk fragments -> registers (once): gk[s][j] = gkq[b*448 + s*64 + ck*4+j]
    float gk[7][4];
    {
        const float4* gp = (const float4*)(gkq + b * 448 + ck * 4);
        #pragma unroll
        for (int s = 0; s < 7; ++s) {
            const float4 u = gp[s * 16];
            gk[s][0] = u.x; gk[s][1] = u.y; gk[s][2] = u.z; gk[s][3] = u.w;
        }
    }
    // per-slot uniform constants (scalar loads)
    const float* ab = aux + b * 14;
    float g1[7], bk[7];
    #pragma unroll
    for (int s = 0; s < 7; ++s) { g1[s] = ab[2 * s]; bk[s] = ab[2 * s + 1]; }

    float Yacc[7][4];
    #pragma unroll
    for (int s = 0; s < 7; ++s)
        #pragma unroll
        for (int j = 0; j < 4; ++j) Yacc[s][j] = 0.f;
    float cacc[7] = {0.f, 0.f, 0.f, 0.f, 0.f, 0.f, 0.f};

    // row = b*4096 + chunk16*256 + wv*64 + g*4 + rsl ; dims ck*4..ck*4+3
    const float* rb = x + (((long)b * 4096) + chunk16 * 256 + wv * 64 + rsl) * 64
                        + ck * 4;
    float4 cur = *(const float4*)(rb);
    #pragma unroll 1
    for (int g = 0; g < 16; ++g) {
        const int gn = (g < 15) ? g + 1 : 15;   // clamp: dead reload (L1-hit)
        const float4 nxt = *(const float4*)(rb + gn * 256);

        const float xv[4] = {cur.x, cur.y, cur.z, cur.w};
        float sum = (xv[0] + xv[1]) + (xv[2] + xv[3]);
        float ss = 0.f;
        #pragma unroll
        for (int j = 0; j < 4; ++j) ss = fmaf(xv[j], xv[j], ss);
        float acc[7];
        #pragma unroll
        for (int s = 0; s < 7; ++s) {
            float a = 0.f;
            #pragma unroll
            for (int j = 0; j < 4; ++j) a = fmaf(xv[j], gk[s][j], a);
            acc[s] = a;
        }
        sum = red16(sum);
        ss  = red16(ss);
        #pragma unroll
        for (int s = 0; s < 7; ++s) acc[s] = red16(acc[s]);

        const float m   = sum * (1.0f / 64.0f);
        const float var = ss * (1.0f / 64.0f) - m * m;
        const float rs  = rsqrtf(var + 1e-5f);
        const float rsm = rs * m;
        float t[7];
        #pragma unroll
        for (int s = 0; s < 7; ++s)
            t[s] = fmaf(rs, acc[s], fmaf(-rsm, g1[s], bk[s]));
        float mx = t[0];
        #pragma unroll
        for (int s = 1; s < 7; ++s) mx = fmaxf(mx, t[s]);
        float e[7], se = 0.f;
        #pragma unroll
        for (int s = 0; s < 7; ++s) {
            e[s] = __builtin_amdgcn_exp2f((t[s] - mx) * L2E);
            se += e[s];
        }
        const float inv = 1.0f / se;
        #pragma unroll
        for (int s = 0; s < 7; ++s) {
            const float w = fmaf(e[s], inv, 1e-8f);
            cacc[s] += w;                       // one row per group per lane
            const float wrs = w * rs;
            #pragma unroll
            for (int j = 0; j < 4; ++j)
                Yacc[s][j] = fmaf(wrs, xv[j], Yacc[s][j]);
        }
        cur = nxt;
    }

    // epilogue: every lane writes its (wv,rsl) partial; no cross-lane needed
    {
        float* yb = &ybuf[wv * 4 + rsl][0];
        #pragma unroll
        for (int s = 0; s < 7; ++s) {
            float4 o;
            o.x = Yacc[s][0]; o.y = Yacc[s][1];
            o.z = Yacc[s][2]; o.w = Yacc[s][3];
            *(float4*)&yb[s * 64 + ck * 4] = o;
        }
        if (ck == 0) {
            #pragma unroll
            for (int s = 0; s < 7; ++s) yb[448 + s] = cacc[s];
            yb[455] = 0.f;
        }
    }
    __syncthreads();
    for (int i = tid; i < 455; i += 256) {
        float v = 0.f;
        #pragma unroll
        for (int p = 0; p < 16; ++p) v += ybuf[p][i];
        Ypart[((long)b * 16 + chunk16) * 456 + i] = v;
    }
}

// ---------------------------------------------------------------------------
// update v2 (R4-exact): one block (256 thr) per (b,s) row. All weight reads
// coalesced (wihT/whhT/WkT pre-transposed). Chain: Y/C reduce -> aoc ->
// u=(aoc@Wv) -> GRU -> MLP -> slots (+ next-iter LN/q/kq or final store).
// grid 448.
// ---------------------------------------------------------------------------
__global__ __launch_bounds__(256) void update_kernel(
    const float* __restrict__ Ypart, float* __restrict__ slots,
    const float* __restrict__ Wv,
    const float* __restrict__ wihT, const float* __restrict__ whhT,
    const float* __restrict__ bih,  const float* __restrict__ bhh,
    const float* __restrict__ w1,   const float* __restrict__ b1,
    const float* __restrict__ w2,   const float* __restrict__ b2,
    const float* __restrict__ lsg,  const float* __restrict__ lsb,
    const float* __restrict__ Wq,   const float* __restrict__ WkT,
    const float* __restrict__ lig,  const float* __restrict__ lib,
    float* __restrict__ gkq, float* __restrict__ aux,
    float* __restrict__ out, int last)
{
    __shared__ float red[4][64];
    __shared__ float c16[16];
    __shared__ float ash[64];
    __shared__ float ush[64];
    __shared__ float hsh[64];
    __shared__ float gish[192], ghsh[192];
    __shared__ float hnsh[64];
    __shared__ float mbsh[128];
    __shared__ float qsh[64];
    const int tid = threadIdx.x, lane = tid & 63, wv = tid >> 6;
    const int r = blockIdx.x;                   // 0..447
    const int b = r / 7, s = r - b * 7;
    const float* Yb = Ypart + (long)b * 16 * 456;

    // stage 1: Y partial sums (4 chunks per wave), colsum parts, h load
    float yp = 0.f;
    #pragma unroll
    for (int c = 0; c < 4; ++c)
        yp += Yb[(wv * 4 + c) * 456 + s * 64 + lane];
    red[wv][lane] = yp;
    if (tid < 16) c16[tid] = Yb[tid * 456 + 448 + s];
    if (tid >= 64 && tid < 128) hsh[tid - 64] = slots[r * 64 + (tid - 64)];
    __syncthreads();

    if (tid < 64) {                             // wave 0
        const float Yd = red[0][lane] + red[1][lane] + red[2][lane] + red[3][lane];
        float C = 0.f;
        #pragma unroll
        for (int c = 0; c < 16; ++c) C += c16[c];
        const float Z = wsum(Yd) * (1.0f / 64.0f);   // Z = sum_d Y / 64
        ash[lane] = (lig[lane] * (Yd - Z) + lib[lane] * C) / C;
    }
    __syncthreads();

    // stage 2: u = aoc @ Wv, i-split over 4 waves
    float up = 0.f;
    #pragma unroll
    for (int i = 0; i < 16; ++i) {
        const int ii = wv * 16 + i;
        up = fmaf(ash[ii], Wv[ii * 64 + lane], up);
    }
    red[wv][lane] = up;
    __syncthreads();
    if (tid < 64) ush[lane] = red[0][lane] + red[1][lane] + red[2][lane] + red[3][lane];
    __syncthreads();

    // stage 3: GRU gates (192 outputs, coalesced transposed weights)
    if (tid < 192) {
        float a1 = bih[tid], a2 = bhh[tid];
        #pragma unroll 8
        for (int i = 0; i < 64; ++i) {
            a1 = fmaf(ush[i], wihT[i * 192 + tid], a1);
            a2 = fmaf(hsh[i], whhT[i * 192 + tid], a2);
        }
        gish[tid] = a1; ghsh[tid] = a2;
    }
    __syncthreads();
    if (tid < 64) {
        const float rr = sigm(gish[tid] + ghsh[tid]);
        const float zz = sigm(gish[64 + tid] + ghsh[64 + tid]);
        const float nn = tanh_(gish[128 + tid] + rr * ghsh[128 + tid]);
        hnsh[tid] = (1.f - zz) * nn + zz * hsh[tid];
    }
    __syncthreads();

    // stage 4: MLP hidden (128 outputs)
    if (tid < 128) {
        float m = b1[tid];
        #pragma unroll 8
        for (int i = 0; i < 64; ++i) m = fmaf(hnsh[i], w1[i * 128 + tid], m);
        mbsh[tid] = fmaxf(m, 0.f);
    }
    __syncthreads();

    // stage 5: MLP out + residual; tail (wave 0 only, no barriers needed)
    if (tid < 64) {
        float o = b2[tid];
        #pragma unroll 8
        for (int t = 0; t < 128; ++t) o = fmaf(mbsh[t], w2[t * 64 + tid], o);
        const float snv = hnsh[tid] + o;
        slots[r * 64 + tid] = snv;
        if (last) {
            out[r * 64 + tid] = snv;
        } else {
            const float mean = wsum(snv) * (1.0f / 64.0f);
            const float d = snv - mean;
            const float var = wsum(d * d) * (1.0f / 64.0f);
            const float rs = rsqrtf(var + 1e-5f);
            const float sn = d * rs * lsg[tid] + lsb[tid];
            ash[tid] = sn;                       // wave0-internal reuse
            float q = 0.f;
            #pragma unroll 8
            for (int i = 0; i < 64; ++i) q = fmaf(ash[i], Wq[i * 64 + tid], q);
            qsh[tid] = q * 0.125f;
            float kq = 0.f;
            #pragma unroll 8
            for (int p = 0; p < 64; ++p) kq = fmaf(WkT[p * 64 + tid], qsh[p], kq);
            const float bk = wsum(lib[tid] * kq);
            const float gk = lig[tid] * kq;
            const float g1 = wsum(gk);
            gkq[r * 64 + tid] = gk;
            if (tid == 0) { aux[r * 2] = g1; aux[r * 2 + 1] = bk; }
        }
    }
}

// ---------------------------------------------------------------------------
extern "C" void kernel_launch(void* const* d_in, const int* in_sizes, int n_in,
                              void* d_out, int out_size, void* d_ws, size_t ws_size,
                              hipStream_t stream)
{
    const float* x   = (const float*)d_in[0];
    const float* lig = (const float*)d_in[1];
    const float* lib = (const float*)d_in[2];
    const float* lsg = (const float*)d_in[3];
    const float* lsb = (const float*)d_in[4];
    const float* s0  = (const float*)d_in[5];
    const float* Wk  = (const float*)d_in[6];
    const float* Wv  = (const float*)d_in[7];
    const float* Wq  = (const float*)d_in[8];
    const float* wih = (const float*)d_in[9];
    const float* whh = (const float*)d_in[10];
    const float* bih = (const float*)d_in[11];
    const float* bhh = (const float*)d_in[12];
    const float* w1  = (const float*)d_in[13];
    const float* b1  = (const float*)d_in[14];
    const float* w2  = (const float*)d_in[15];
    const float* b2  = (const float*)d_in[16];

    float* f = (float*)d_ws;
    float* gkq   = f; f += 448 * 64;
    float* aux   = f; f += 448 * 2;
    float* slots = f; f += 448 * 64;
    float* Ypart = f; f += (long)64 * 16 * 456;
    float* wihT  = f; f += 64 * 192;
    float* whhT  = f; f += 64 * 192;
    float* WkT   = f; f += 64 * 64;

    init_kernel<<<112, 256, 0, stream>>>(s0, lsg, lsb, Wq, Wk, lig, lib,
                                         wih, whh, slots, gkq, aux,
                                         wihT, whhT, WkT);
    for (int it = 0; it < 3; ++it) {
        attn_kernel<<<1024, 256, 0, stream>>>(x, gkq, aux, Ypart);
        update_kernel<<<448, 256, 0, stream>>>(
            Ypart, slots, Wv, wihT, whhT, bih, bhh, w1, b1, w2, b2,
            lsg, lsb, Wq, WkT, lig, lib, gkq, aux,
            (float*)d_out, it == 2);
    }
}